// Round 3
// baseline (648.202 us; speedup 1.0000x reference)
//
#include <hip/hip_runtime.h>

#define N_NEUR 512
#define B_SZ   16
#define T_STEPS 32
#define NIN    32
#define NOUT   16
#define CAPC   84   // chem nnz/row cap (mean 48.6, sd 6.63 -> +5.3 sigma)
#define CAPG   52   // gj nnz/row cap   (mean 25.6, sd 4.93 -> +5.4 sigma)
#define CPC2   (CAPC/2)
#define CPG2   (CAPG/2)
#define LOG2E  1.4426950408889634f

__device__ __forceinline__ float rcp_fast(float x) {
#if __has_builtin(__builtin_amdgcn_rcpf)
    return __builtin_amdgcn_rcpf(x);
#else
    return 1.0f / x;
#endif
}
__device__ __forceinline__ float exp2_fast(float x) {
#if __has_builtin(__builtin_amdgcn_exp2f)
    return __builtin_amdgcn_exp2f(x);
#else
    return exp2f(x);
#endif
}

// prep1: per row, softplus + mask + ballot-compact into dense per-row tmp CSR.
__global__ __launch_bounds__(64) void prep1_kernel(
    const float* __restrict__ W,
    const float* __restrict__ mex,
    const float* __restrict__ min_,
    const float* __restrict__ mgj,
    int* __restrict__ key_arr, int* __restrict__ ccA, int* __restrict__ cgA,
    int2* __restrict__ tmpC, int2* __restrict__ tmpG)
{
    const int row  = blockIdx.x;
    const int lane = threadIdx.x;
    const unsigned long long below = (1ull << lane) - 1ull;
    int bc = 0, bg = 0;
    for (int c0 = 0; c0 < N_NEUR; c0 += 64) {
        const int col = c0 + lane;
        const int off = row * N_NEUR + col;
        const float w  = W[off];
        const float sp = fmaxf(w, 0.0f) + log1pf(__expf(-fabsf(w)));  // softplus
        const float dm = mex[off] - min_[off];                         // in {-1,0,1}
        bool a = (dm != 0.0f);
        unsigned long long m = __ballot(a);
        int idx = bc + __popcll(m & below);
        if (a && idx < CAPC)
            tmpC[row * CAPC + idx] = make_int2(col, __float_as_int(sp * dm));
        bc += __popcll(m);

        const float g = mgj[off];
        bool ag = (g != 0.0f);
        m = __ballot(ag);
        idx = bg + __popcll(m & below);
        if (ag && idx < CAPG)
            tmpG[row * CAPG + idx] = make_int2(col, __float_as_int(sp * g));
        bg += __popcll(m);
    }
    if (lane == 0) {
        int cc = min(bc, CAPC), cg = min(bg, CAPG);
        ccA[row] = cc; cgA[row] = cg; key_arr[row] = cc + cg;
    }
}

// prep2: per row d, compute rank (sort by key asc, index tie-break), write
// order[rank]=d, and emit the final position-indexed register-load layout:
//   weights f32 at (wv*CAP + k)*64 + laneP ; cols packed 2xu16 per dword.
// Slots beyond cc/cg are zero-padded.
__global__ __launch_bounds__(64) void prep2_kernel(
    const int* __restrict__ key_arr, const int* __restrict__ ccA, const int* __restrict__ cgA,
    const int2* __restrict__ tmpC, const int2* __restrict__ tmpG,
    int* __restrict__ order,
    float* __restrict__ wCf, unsigned* __restrict__ cpCf,
    float* __restrict__ wGf, unsigned* __restrict__ cpGf)
{
    __shared__ int colC[CAPC];
    __shared__ int colG[CAPG];
    const int d    = blockIdx.x;
    const int lane = threadIdx.x;
    const int kd   = key_arr[d];
    int r = 0;
    for (int j = lane; j < N_NEUR; j += 64) {
        int kj = key_arr[j];
        r += (kj < kd) || (kj == kd && j < d);
    }
    #pragma unroll
    for (int i = 1; i < 64; i <<= 1) r += __shfl_xor(r, i);
    if (lane == 0) order[r] = d;

    const int wv = r >> 6, lp = r & 63;
    const int cc = ccA[d], cg = cgA[d];
    for (int k = lane; k < CAPC; k += 64) {
        int2 e = (k < cc) ? tmpC[d * CAPC + k] : make_int2(0, 0);
        wCf[(wv * CAPC + k) * 64 + lp] = __int_as_float(e.y);
        colC[k] = e.x;
    }
    for (int k = lane; k < CAPG; k += 64) {
        int2 e = (k < cg) ? tmpG[d * CAPG + k] : make_int2(0, 0);
        wGf[(wv * CAPG + k) * 64 + lp] = __int_as_float(e.y);
        colG[k] = e.x;
    }
    __syncthreads();
    for (int kp = lane; kp < CPC2; kp += 64)
        cpCf[(wv * CPC2 + kp) * 64 + lp] =
            (unsigned)colC[2 * kp] | ((unsigned)colC[2 * kp + 1] << 16);
    for (int kp = lane; kp < CPG2; kp += 64)
        cpGf[(wv * CPG2 + kp) * 64 + lp] =
            (unsigned)colG[2 * kp] | ((unsigned)colG[2 * kp + 1] << 16);
}

// main: one block per batch, 512 threads = 1 per neuron (sorted assignment).
// Entry lists live in REGISTERS for all 32 steps: no global loads in the loop.
__global__ __launch_bounds__(512, 2) void recur_kernel(
    const float* __restrict__ obs,
    const float* __restrict__ thr,
    const float* __restrict__ dec,
    const int* __restrict__ order, const int* __restrict__ ccA, const int* __restrict__ cgA,
    const float* __restrict__ wCf, const unsigned* __restrict__ cpCf,
    const float* __restrict__ wGf, const unsigned* __restrict__ cpGf,
    float* __restrict__ out)
{
    __shared__ float Ob[2][N_NEUR];
    __shared__ float Eb[2][N_NEUR];

    const int b    = blockIdx.x;
    const int tid  = threadIdx.x;
    const int wv   = tid >> 6;
    const int lane = tid & 63;

    const int d = order[tid];
    const int cc = ccA[d];
    const int cg = cgA[d];
    const float thr_d = thr[d];
    const float dec_d = dec[d];

    int ccw = cc, cgw = cg;
    #pragma unroll
    for (int i = 1; i < 64; i <<= 1) {
        ccw = max(ccw, __shfl_xor(ccw, i));
        cgw = max(cgw, __shfl_xor(cgw, i));
    }

    // load lists into registers (zero-padded beyond cc/cg)
    float    wC[CAPC]; unsigned cpC[CPC2];
    float    wG[CAPG]; unsigned cpG[CPG2];
    #pragma unroll
    for (int k = 0; k < CAPC; ++k) wC[k] = wCf[(wv * CAPC + k) * 64 + lane];
    #pragma unroll
    for (int kp = 0; kp < CPC2; ++kp) cpC[kp] = cpCf[(wv * CPC2 + kp) * 64 + lane];
    #pragma unroll
    for (int k = 0; k < CAPG; ++k) wG[k] = wGf[(wv * CAPG + k) * 64 + lane];
    #pragma unroll
    for (int kp = 0; kp < CPG2; ++kp) cpG[kp] = cpGf[(wv * CPG2 + kp) * 64 + lane];

    Ob[0][tid] = 0.0f;
    Eb[0][tid] = 0.0f;
    const bool wr = (d >= NIN) && (d < NIN + NOUT);
    float* outp = out + (size_t)b * T_STEPS * NOUT + (d - NIN);
    const float* obs_b = obs + b * (T_STEPS * NIN);
    float ob_next = (tid < NIN) ? obs_b[tid] : 0.0f;
    int p = 0;
    __syncthreads();

    for (int t = 0; t < T_STEPS; ++t) {
        if (tid < NIN) {                  // inject observation (read buffer)
            Ob[p][tid] = ob_next;
            Eb[p][tid] = ob_next;
        }
        __syncthreads();
        float ob_pf = (t + 1 < T_STEPS && tid < NIN) ? obs_b[(t + 1) * NIN + tid] : 0.0f;

        const float E_d = Eb[p][d];
        float acc = 0.0f;
        // chem
        #pragma unroll
        for (int k = 0; k < CAPC; ++k) {
            if (k >= ccw) break;                        // wave-uniform
            unsigned pk = cpC[k >> 1];
            int col = (k & 1) ? (int)(pk >> 16) : (int)(pk & 0xffff);
            if (k < cc)                                 // per-lane predicate
                acc = fmaf(wC[k], Ob[p][col], acc);
        }
        // gj
        const float cE = -20.0f * LOG2E * E_d;
        #pragma unroll
        for (int k = 0; k < CAPG; ++k) {
            if (k >= cgw) break;
            unsigned pk = cpG[k >> 1];
            int col = (k & 1) ? (int)(pk >> 16) : (int)(pk & 0xffff);
            if (k < cg) {
                float Os  = Ob[p][col];
                float f   = fmaf(20.0f * LOG2E, Os, cE);
                float tnh = 1.0f - 2.0f * rcp_fast(1.0f + exp2_fast(f));
                acc = fmaf(wG[k] * Os, tnh, acc);
            }
        }

        // epilogue
        float curr = fminf(fmaxf(E_d + acc, -10.0f), 10.0f);
        float z = curr - thr_d;
        float O_new = (z >= 0.0f) ? z : 0.01f * z;
        float fg = rcp_fast(1.0f + exp2_fast(-10.0f * LOG2E * z));
        float dg = rcp_fast(1.0f + exp2_fast(-5.0f * LOG2E * (fabsf(E_d - curr) - 0.01f)));
        float E_nf  = dg * curr + (1.0f - dg) * (E_d - dec_d);
        float E_new = fg * O_new + (1.0f - fg) * E_nf;

        const int q = p ^ 1;
        Eb[q][d] = E_new;
        Ob[q][d] = O_new;
        if (wr) outp[t * NOUT] = E_new;
        ob_next = ob_pf;
        __syncthreads();
        p = q;
    }
}

extern "C" void kernel_launch(void* const* d_in, const int* in_sizes, int n_in,
                              void* d_out, int out_size, void* d_ws, size_t ws_size,
                              hipStream_t stream)
{
    const float* obs  = (const float*)d_in[0];
    const float* W    = (const float*)d_in[1];
    const float* thr  = (const float*)d_in[2];
    const float* dec  = (const float*)d_in[3];
    const float* mex  = (const float*)d_in[4];
    const float* min_ = (const float*)d_in[5];
    const float* mgj  = (const float*)d_in[6];
    float* out = (float*)d_out;

    char* ws = (char*)d_ws;
    int*   key_arr = (int*)(ws);
    int*   ccA     = (int*)(ws + 2048);
    int*   cgA     = (int*)(ws + 4096);
    int*   order   = (int*)(ws + 6144);
    int2*  tmpC    = (int2*)(ws + 8192);                         // 512*84*8 = 344064
    int2*  tmpG    = (int2*)(ws + 8192 + 344064);                // 512*52*8 = 212992
    float* wCf     = (float*)(ws + 565248);                      // 84*512*4 = 172032
    unsigned* cpCf = (unsigned*)(ws + 737280);                   // 42*512*4 =  86016
    float* wGf     = (float*)(ws + 823296);                      // 52*512*4 = 106496
    unsigned* cpGf = (unsigned*)(ws + 929792);                   // 26*512*4 =  53248
    // total ws use: ~983 KB

    prep1_kernel<<<N_NEUR, 64, 0, stream>>>(W, mex, min_, mgj,
                                            key_arr, ccA, cgA, tmpC, tmpG);
    prep2_kernel<<<N_NEUR, 64, 0, stream>>>(key_arr, ccA, cgA, tmpC, tmpG,
                                            order, wCf, cpCf, wGf, cpGf);
    recur_kernel<<<B_SZ, 512, 0, stream>>>(obs, thr, dec,
                                           order, ccA, cgA,
                                           wCf, cpCf, wGf, cpGf, out);
}

// Round 4
// 185.371 us; speedup vs baseline: 3.4968x; 3.4968x over previous
//
#include <hip/hip_runtime.h>

#define N_NEUR 512
#define B_SZ   16
#define T_STEPS 32
#define NIN    32
#define NOUT   16
#define CAPC   84   // chem nnz/row cap (mean 48.6, sd 6.63)
#define CAPG   52   // gj nnz/row cap   (mean 25.6, sd 4.93)
#define MC     42   // per-thread chem entries (h splits CSR evens/odds)
#define MG     26
#define MCP    21   // packed col words per thread
#define MGP    13
#define LOG2E  1.4426950408889634f

__device__ __forceinline__ float rcp_fast(float x) {
#if __has_builtin(__builtin_amdgcn_rcpf)
    return __builtin_amdgcn_rcpf(x);
#else
    return 1.0f / x;
#endif
}
__device__ __forceinline__ float exp2_fast(float x) {
#if __has_builtin(__builtin_amdgcn_exp2f)
    return __builtin_amdgcn_exp2f(x);
#else
    return exp2f(x);
#endif
}

// prep1: per row, softplus + mask + ballot-compact into dense per-row tmp CSR.
__global__ __launch_bounds__(64) void prep1_kernel(
    const float* __restrict__ W,
    const float* __restrict__ mex,
    const float* __restrict__ min_,
    const float* __restrict__ mgj,
    int* __restrict__ key_arr, int* __restrict__ ccA, int* __restrict__ cgA,
    int2* __restrict__ tmpC, int2* __restrict__ tmpG)
{
    const int row  = blockIdx.x;
    const int lane = threadIdx.x;
    const unsigned long long below = (1ull << lane) - 1ull;
    int bc = 0, bg = 0;
    for (int c0 = 0; c0 < N_NEUR; c0 += 64) {
        const int col = c0 + lane;
        const int off = row * N_NEUR + col;
        const float w  = W[off];
        const float sp = fmaxf(w, 0.0f) + log1pf(__expf(-fabsf(w)));  // softplus
        const float dm = mex[off] - min_[off];                         // in {-1,0,1}
        bool a = (dm != 0.0f);
        unsigned long long m = __ballot(a);
        int idx = bc + __popcll(m & below);
        if (a && idx < CAPC)
            tmpC[row * CAPC + idx] = make_int2(col, __float_as_int(sp * dm));
        bc += __popcll(m);

        const float g = mgj[off];
        bool ag = (g != 0.0f);
        m = __ballot(ag);
        idx = bg + __popcll(m & below);
        if (ag && idx < CAPG)
            tmpG[row * CAPG + idx] = make_int2(col, __float_as_int(sp * g));
        bg += __popcll(m);
    }
    if (lane == 0) {
        int cc = min(bc, CAPC), cg = min(bg, CAPG);
        ccA[row] = cc; cgA[row] = cg; key_arr[row] = cc + cg;
    }
}

// prep2: rank rows by nnz (asc), emit transposed zero-padded layout for the
// main kernel's register loads. Thread tid=2r+h in main: wv=tid>>6, lane=tid&63.
// Weight slot for CSR idx s of neuron rank r: wT[(wv*MC + (s>>1))*64 + 2*(r&31) + (s&1)].
// Packed col word (kp,h): byte-scaled cols of CSR (4kp+h, 4kp+2+h).
__global__ __launch_bounds__(64) void prep2_kernel(
    const int* __restrict__ key_arr, const int* __restrict__ ccA, const int* __restrict__ cgA,
    const int2* __restrict__ tmpC, const int2* __restrict__ tmpG,
    int* __restrict__ order,
    float* __restrict__ wCt, unsigned* __restrict__ cpCt,
    float* __restrict__ wGt, unsigned* __restrict__ cpGt)
{
    __shared__ int colC[CAPC];
    __shared__ int colG[CAPG];
    const int d    = blockIdx.x;
    const int lane = threadIdx.x;
    const int kd   = key_arr[d];
    int r = 0;
    for (int j = lane; j < N_NEUR; j += 64) {
        int kj = key_arr[j];
        r += (kj < kd) || (kj == kd && j < d);
    }
    #pragma unroll
    for (int i = 1; i < 64; i <<= 1) r += __shfl_xor(r, i);
    if (lane == 0) order[r] = d;

    const int wv = r >> 5;            // tid=2r -> wv=(2r)>>6 = r>>5
    const int Lb = 2 * (r & 31);
    const int cc = ccA[d], cg = cgA[d];

    for (int k = lane; k < CAPC; k += 64) colC[k] = 0;
    for (int k = lane; k < CAPG; k += 64) colG[k] = 0;
    __syncthreads();
    for (int k = lane; k < cc; k += 64) colC[k] = tmpC[d * CAPC + k].x;
    for (int k = lane; k < cg; k += 64) colG[k] = tmpG[d * CAPG + k].x;

    for (int s = lane; s < CAPC; s += 64) {
        float w = (s < cc) ? __int_as_float(tmpC[d * CAPC + s].y) : 0.0f;
        wCt[(wv * MC + (s >> 1)) * 64 + Lb + (s & 1)] = w;
    }
    for (int s = lane; s < CAPG; s += 64) {
        float w = (s < cg) ? __int_as_float(tmpG[d * CAPG + s].y) : 0.0f;
        wGt[(wv * MG + (s >> 1)) * 64 + Lb + (s & 1)] = w;
    }
    __syncthreads();
    for (int u = lane; u < 2 * MCP; u += 64) {
        int kp = u >> 1, h = u & 1;
        unsigned c0 = (unsigned)colC[4 * kp + h] << 2;
        unsigned c1 = (unsigned)colC[4 * kp + 2 + h] << 2;   // 4*20+3=83 < 84
        cpCt[(wv * MCP + kp) * 64 + Lb + h] = c0 | (c1 << 16);
    }
    for (int u = lane; u < 2 * MGP; u += 64) {
        int kp = u >> 1, h = u & 1;
        unsigned c0 = (unsigned)colG[4 * kp + h] << 2;
        unsigned c1 = (unsigned)colG[4 * kp + 2 + h] << 2;   // 4*12+3=51 < 52
        cpGt[(wv * MGP + kp) * 64 + Lb + h] = c0 | (c1 << 16);
    }
}

#define CHEM_K(k) {                                                         \
    unsigned pk = cpC[(k) >> 1];                                            \
    unsigned off = ((k) & 1) ? (pk >> 16) : (pk & 0xffffu);                 \
    acc = fmaf(wC[k], *(const float*)((const char*)ObP + off), acc); }

#define GJ_K(k) {                                                           \
    unsigned pk = cpG[(k) >> 1];                                            \
    unsigned off = ((k) & 1) ? (pk >> 16) : (pk & 0xffffu);                 \
    float Os = *(const float*)((const char*)ObP + off);                     \
    float f = fmaf(20.0f * LOG2E, Os, cE);                                  \
    float tnh = 1.0f - 2.0f * rcp_fast(1.0f + exp2_fast(f));                \
    acc = fmaf(wG[k] * Os, tnh, acc); }

// main: one block per batch, 1024 threads = 2 per neuron (sorted by nnz).
// Entry lists in REGISTERS (fixed-trip fully-unrolled loops, constant idx —
// the round-3 dynamic `break` caused scratch spill; chunk guards below are
// wave-uniform scalar branches with CONSTANT register indices).
__global__ __launch_bounds__(1024, 1) void recur_kernel(
    const float* __restrict__ obs,
    const float* __restrict__ thr,
    const float* __restrict__ dec,
    const int* __restrict__ order, const int* __restrict__ ccA, const int* __restrict__ cgA,
    const float* __restrict__ wCt, const unsigned* __restrict__ cpCt,
    const float* __restrict__ wGt, const unsigned* __restrict__ cpGt,
    float* __restrict__ out)
{
    __shared__ float Ob[2][N_NEUR];
    __shared__ float Eb[2][N_NEUR];

    const int b    = blockIdx.x;
    const int tid  = threadIdx.x;
    const int h    = tid & 1;
    const int r    = tid >> 1;            // rank
    const int wv   = tid >> 6;
    const int lane = tid & 63;

    const int d = order[r];
    const int cc = ccA[d];
    const int cg = cgA[d];
    const float thr_d = thr[d];
    const float dec_d = dec[d];

    int ccw = cc, cgw = cg;
    #pragma unroll
    for (int i = 1; i < 64; i <<= 1) {
        ccw = max(ccw, __shfl_xor(ccw, i));
        cgw = max(cgw, __shfl_xor(cgw, i));
    }
    const int mCw = __builtin_amdgcn_readfirstlane((ccw + 1) >> 1);
    const int mGw = __builtin_amdgcn_readfirstlane((cgw + 1) >> 1);

    // register-resident lists (zero-padded)
    float wC[MC]; unsigned cpC[MCP];
    float wG[MG]; unsigned cpG[MGP];
    #pragma unroll
    for (int k = 0; k < MC; ++k)  wC[k]  = wCt[(wv * MC + k) * 64 + lane];
    #pragma unroll
    for (int k = 0; k < MCP; ++k) cpC[k] = cpCt[(wv * MCP + k) * 64 + lane];
    #pragma unroll
    for (int k = 0; k < MG; ++k)  wG[k]  = wGt[(wv * MG + k) * 64 + lane];
    #pragma unroll
    for (int k = 0; k < MGP; ++k) cpG[k] = cpGt[(wv * MGP + k) * 64 + lane];

    if (h == 0) { Ob[0][d] = 0.0f; Eb[0][d] = 0.0f; }
    const bool wr = (h == 0) && (d >= NIN) && (d < NIN + NOUT);
    float* outp = out + (size_t)b * T_STEPS * NOUT + (d - NIN);
    const float* obs_b = obs + b * (T_STEPS * NIN);
    const bool inj = (h == 0) && (d < NIN);
    float ob_next = inj ? obs_b[d] : 0.0f;
    int p = 0;
    __syncthreads();

    for (int t = 0; t < T_STEPS; ++t) {
        if (inj) {
            Ob[p][d] = ob_next;
            Eb[p][d] = ob_next;
        }
        __syncthreads();
        float ob_pf = (t + 1 < T_STEPS && inj) ? obs_b[(t + 1) * NIN + d] : 0.0f;

        const float* ObP = Ob[p];
        const float E_d = Eb[p][d];
        float acc = 0.0f;
        // chem: chunks of 8, wave-uniform guards, constant register indices
        { CHEM_K(0) CHEM_K(1) CHEM_K(2) CHEM_K(3) CHEM_K(4) CHEM_K(5) CHEM_K(6) CHEM_K(7) }
        if (8 < mCw)  { CHEM_K(8)  CHEM_K(9)  CHEM_K(10) CHEM_K(11) CHEM_K(12) CHEM_K(13) CHEM_K(14) CHEM_K(15) }
        if (16 < mCw) { CHEM_K(16) CHEM_K(17) CHEM_K(18) CHEM_K(19) CHEM_K(20) CHEM_K(21) CHEM_K(22) CHEM_K(23) }
        if (24 < mCw) { CHEM_K(24) CHEM_K(25) CHEM_K(26) CHEM_K(27) CHEM_K(28) CHEM_K(29) CHEM_K(30) CHEM_K(31) }
        if (32 < mCw) { CHEM_K(32) CHEM_K(33) CHEM_K(34) CHEM_K(35) CHEM_K(36) CHEM_K(37) CHEM_K(38) CHEM_K(39) }
        if (40 < mCw) { CHEM_K(40) CHEM_K(41) }
        // gj
        const float cE = -20.0f * LOG2E * E_d;
        { GJ_K(0) GJ_K(1) GJ_K(2) GJ_K(3) GJ_K(4) GJ_K(5) GJ_K(6) GJ_K(7) }
        if (8 < mGw)  { GJ_K(8)  GJ_K(9)  GJ_K(10) GJ_K(11) GJ_K(12) GJ_K(13) GJ_K(14) GJ_K(15) }
        if (16 < mGw) { GJ_K(16) GJ_K(17) GJ_K(18) GJ_K(19) GJ_K(20) GJ_K(21) GJ_K(22) GJ_K(23) }
        if (24 < mGw) { GJ_K(24) GJ_K(25) }

        acc += __shfl_xor(acc, 1);

        // epilogue (both halves compute; h==0 writes)
        float curr = fminf(fmaxf(E_d + acc, -10.0f), 10.0f);
        float z = curr - thr_d;
        float O_new = (z >= 0.0f) ? z : 0.01f * z;
        float fg = rcp_fast(1.0f + exp2_fast(-10.0f * LOG2E * z));
        float dg = rcp_fast(1.0f + exp2_fast(-5.0f * LOG2E * (fabsf(E_d - curr) - 0.01f)));
        float E_nf  = dg * curr + (1.0f - dg) * (E_d - dec_d);
        float E_new = fg * O_new + (1.0f - fg) * E_nf;

        const int q = p ^ 1;
        if (h == 0) {
            Eb[q][d] = E_new;
            Ob[q][d] = O_new;
            if (wr) outp[t * NOUT] = E_new;
        }
        ob_next = ob_pf;
        __syncthreads();
        p = q;
    }
}

extern "C" void kernel_launch(void* const* d_in, const int* in_sizes, int n_in,
                              void* d_out, int out_size, void* d_ws, size_t ws_size,
                              hipStream_t stream)
{
    const float* obs  = (const float*)d_in[0];
    const float* W    = (const float*)d_in[1];
    const float* thr  = (const float*)d_in[2];
    const float* dec  = (const float*)d_in[3];
    const float* mex  = (const float*)d_in[4];
    const float* min_ = (const float*)d_in[5];
    const float* mgj  = (const float*)d_in[6];
    float* out = (float*)d_out;

    char* ws = (char*)d_ws;
    int*   key_arr = (int*)(ws);
    int*   ccA     = (int*)(ws + 2048);
    int*   cgA     = (int*)(ws + 4096);
    int*   order   = (int*)(ws + 6144);
    int2*  tmpC    = (int2*)(ws + 8192);                   // 512*84*8 = 344064
    int2*  tmpG    = (int2*)(ws + 8192 + 344064);          // 512*52*8 = 212992
    float* wCt     = (float*)(ws + 565248);                // 16*42*64*4 = 172032
    unsigned* cpCt = (unsigned*)(ws + 737280);             // 16*21*64*4 =  86016
    float* wGt     = (float*)(ws + 823296);                // 16*26*64*4 = 106496
    unsigned* cpGt = (unsigned*)(ws + 929792);             // 16*13*64*4 =  53248
    // total ws use: ~983 KB

    prep1_kernel<<<N_NEUR, 64, 0, stream>>>(W, mex, min_, mgj,
                                            key_arr, ccA, cgA, tmpC, tmpG);
    prep2_kernel<<<N_NEUR, 64, 0, stream>>>(key_arr, ccA, cgA, tmpC, tmpG,
                                            order, wCt, cpCt, wGt, cpGt);
    recur_kernel<<<B_SZ, 1024, 0, stream>>>(obs, thr, dec,
                                            order, ccA, cgA,
                                            wCt, cpCt, wGt, cpGt, out);
}